// Round 9
// baseline (101.897 us; speedup 1.0000x reference)
//
#include <hip/hip_runtime.h>

// LIF neuron forward, v4: ping-pong consumers with register-resident chunks.
// V = leak*V + I; spike = (V >= 1); V -= spike.
// current: [B=8, S=4096, D=1024] f32, membrane: [B, D] f32.
// Outputs concatenated: spikes [B,S,D] then mem_final [B,D], all f32.
//
// r8 evidence (96.7us): phase=3600cy but consumer work only ~1500cy; chain
// kept restarting from LDS stalls + all-wave barrier coupling. v4: two
// consumer waves alternate chunks. Active turn = pure register chain
// (input pre-staged into cin[64] VGPRs during the off-turn) + direct
// global spike stores (off-chain). Off turn = 64x ds_read_b32 prefetch of
// the next chunk. Membrane hands off via 1 float/lane in LDS. Wave 2 is
// the HBM->LDS producer (1KB global_load_lds, 2 chunks ahead, 3-slot ring).
//
// Numerics (validated r5-r8, absmax 7.6e-6): forward spike == hard
// threshold exactly in fp32; fp contract(off) pins mul-then-add rounding;
// mem = f ? (v-1) : v is bit-identical to v - spike.

#define LIF_B 8
#define LIF_S 4096
#define LIF_D 1024
#define CHUNK 64
#define NH    (LIF_S / CHUNK)   // 64

typedef __attribute__((address_space(3))) unsigned int lds_uint;
typedef const __attribute__((address_space(1))) unsigned int glb_uint;

__global__ __launch_bounds__(192, 1) void lif_pp_kernel(
    const float* __restrict__ current,
    const float* __restrict__ membrane,
    float* __restrict__ spikes,
    float* __restrict__ mem_out)
{
    #pragma clang fp contract(off)

    __shared__ __align__(16) float ring[3][CHUNK][64];   // 48 KB input ring
    __shared__ float memx[64];                           // membrane handoff

    const int wid  = threadIdx.x >> 6;   // 0,1 = ping-pong consumers, 2 = producer
    const int lane = threadIdx.x & 63;
    const int blk  = blockIdx.x;         // 0..127
    const int bb   = blk >> 4;           // batch
    const int ch0  = (blk & 15) * 64;

    const float* gbase = current + (size_t)bb * LIF_S * LIF_D + ch0;
    float*       sbase = spikes  + (size_t)bb * LIF_S * LIF_D + ch0 + lane;

    // producer fused 4-row mapping: lane L -> row (L>>4), float col (L&15)*4
    const int prow = lane >> 4;
    const int pcol = (lane & 15) * 4;

    float cin[CHUNK];   // register-resident input chunk (static indexing only)
    float mem = 0.0f;

    // ---- prologue: producer stages chunks 0 and 1; consumer A loads membrane
    if (wid == 2) {
        #pragma unroll
        for (int f = 0; f < CHUNK / 4; ++f) {
            const float* src = gbase + (size_t)(4 * f + prow) * LIF_D + pcol;
            __builtin_amdgcn_global_load_lds((glb_uint*)(const void*)src,
                (lds_uint*)(void*)&ring[0][4 * f][0], 16, 0, 0);
        }
        #pragma unroll
        for (int f = 0; f < CHUNK / 4; ++f) {
            const float* src = gbase + (size_t)(CHUNK + 4 * f + prow) * LIF_D + pcol;
            __builtin_amdgcn_global_load_lds((glb_uint*)(const void*)src,
                (lds_uint*)(void*)&ring[1][4 * f][0], 16, 0, 0);
        }
    } else if (wid == 0) {
        mem = membrane[bb * LIF_D + ch0 + lane];
    }
    __syncthreads();   // chunks 0,1 resident

    for (int h = 0; h < NH; ++h) {
        const int role = h & 1;
        if (wid == role) {
            // ---- active consumer: pure-register 64-step chain ----
            if (h == 0) {   // only turn 0 lacks a prefetched cin
                #pragma unroll
                for (int j = 0; j < CHUNK; ++j) cin[j] = ring[0][j][lane];
            } else {
                mem = memx[lane];
            }
            float* op = sbase + (size_t)h * CHUNK * LIF_D;
            #pragma unroll
            for (int j = 0; j < CHUNK; ++j) {
                const float v = 0.9f * mem + cin[j];   // mul-then-add (no FMA)
                const float w = v - 1.0f;              // off critical path
                const bool  f = (v >= 1.0f);
                op[(size_t)j * LIF_D] = f ? 1.0f : 0.0f;  // store off-chain
                mem = f ? w : v;                       // soft reset
            }
            if (h == NH - 1) mem_out[bb * LIF_D + ch0 + lane] = mem;
            else             memx[lane] = mem;
        } else if (wid == (role ^ 1)) {
            // ---- off consumer: prefetch chunk h+1 LDS -> registers ----
            if (h + 1 < NH) {
                const float* rb = &ring[(h + 1) % 3][0][lane];
                #pragma unroll
                for (int j = 0; j < CHUNK; ++j) cin[j] = rb[j * 64];
            }
        } else {
            // ---- producer: stage chunk h+2 into ring slot (h+2)%3 ----
            if (h + 2 < NH) {
                const int slot = (h + 2) % 3;
                const int tb   = (h + 2) * CHUNK;
                #pragma unroll
                for (int f = 0; f < CHUNK / 4; ++f) {
                    const float* src = gbase
                        + (size_t)(tb + 4 * f + prow) * LIF_D + pcol;
                    __builtin_amdgcn_global_load_lds((glb_uint*)(const void*)src,
                        (lds_uint*)(void*)&ring[slot][4 * f][0], 16, 0, 0);
                }
            }
        }
        __syncthreads();
    }
}

extern "C" void kernel_launch(void* const* d_in, const int* in_sizes, int n_in,
                              void* d_out, int out_size, void* d_ws, size_t ws_size,
                              hipStream_t stream) {
    const float* current  = (const float*)d_in[0];   // [8, 4096, 1024]
    const float* membrane = (const float*)d_in[1];   // [8, 1024]

    float* spikes  = (float*)d_out;                                 // [8,4096,1024]
    float* mem_out = (float*)d_out + (size_t)LIF_B * LIF_S * LIF_D; // [8,1024]

    dim3 block(192);                  // w0/w1 ping-pong consumers, w2 producer
    dim3 grid(LIF_B * LIF_D / 64);    // 128 blocks (64 channels each)

    hipLaunchKernelGGL(lif_pp_kernel, grid, block, 0, stream,
                       current, membrane, spikes, mem_out);
}

// Round 10
// 94.256 us; speedup vs baseline: 1.0811x; 1.0811x over previous
//
#include <hip/hip_runtime.h>

// LIF neuron forward, v5: 3-stage pipeline + counted-vmcnt barriers (T4).
// V = leak*V + I; spike = (V >= 1); V -= spike.
// current: [B=8, S=4096, D=1024] f32, membrane: [B, D] f32.
// Outputs concatenated: spikes [B,S,D] then mem_final [B,D], all f32.
//
// r8 (96.7us): __syncthreads forces producer vmcnt(0) drain every phase ->
// each phase pays exposed HBM latency. r9 (101.9us): "register-resident"
// chunks spilled (VGPR_Count=68 < 64-elem array) -> dead end.
// v5 = r8 structure, raw s_barrier, producer 3 chunks ahead in a 4-slot
// ring waiting only vmcnt(32) (oldest chunk retired, 32 loads stay in
// flight across the barrier); consumer/writers wait only lgkmcnt(0).
// No wave drains global stores at any barrier.
//
// Numerics (validated r5-r9, absmax 7.6e-6): forward spike == hard
// threshold exactly in fp32; fp contract(off) pins mul-then-add rounding.

#define LIF_B 8
#define LIF_S 4096
#define LIF_D 1024
#define CHUNK 64
#define NH    (LIF_S / CHUNK)   // 64

typedef __attribute__((address_space(3))) unsigned int lds_uint;
typedef const __attribute__((address_space(1))) unsigned int glb_uint;

// stage one 16KB chunk (64 rows x 64 ch) with 16 x 1KB global_load_lds.
// lane L -> row (L>>4), float col (L&15)*4 ; LDS dest linear (m173 pattern).
__device__ __forceinline__ void stage_chunk(const float* gbase, int tb,
                                            int prow, int pcol,
                                            float* slotbase) {
    #pragma unroll
    for (int f = 0; f < CHUNK / 4; ++f) {
        const float* src = gbase + (size_t)(tb + 4 * f + prow) * LIF_D + pcol;
        __builtin_amdgcn_global_load_lds(
            (glb_uint*)(const void*)src,
            (lds_uint*)(void*)(slotbase + (size_t)4 * f * 64), 16, 0, 0);
    }
}

__global__ __launch_bounds__(256, 1) void lif_v5_kernel(
    const float* __restrict__ current,
    const float* __restrict__ membrane,
    float* __restrict__ spikes,
    float* __restrict__ mem_out)
{
    #pragma clang fp contract(off)

    __shared__ __align__(16) float in_ring [4][CHUNK][64];   // 64 KB
    __shared__ __align__(16) float out_ring[2][CHUNK][64];   // 32 KB

    const int wid  = threadIdx.x >> 6;   // 0=consumer 1=producer 2,3=writers
    const int lane = threadIdx.x & 63;
    const int blk  = blockIdx.x;         // 0..127
    const int bb   = blk >> 4;           // batch
    const int ch0  = (blk & 15) * 64;

    const float* gbase = current + (size_t)bb * LIF_S * LIF_D + ch0;
    float*       sbase = spikes  + (size_t)bb * LIF_S * LIF_D + ch0;

    const int prow = lane >> 4;          // fused 4-row mapping
    const int pcol = (lane & 15) * 4;

    float mem = 0.0f;

    // ---- prologue: producer stages chunks 0..2; consumer loads membrane ----
    if (wid == 1) {
        stage_chunk(gbase, 0 * CHUNK, prow, pcol, &in_ring[0][0][0]);
        stage_chunk(gbase, 1 * CHUNK, prow, pcol, &in_ring[1][0][0]);
        stage_chunk(gbase, 2 * CHUNK, prow, pcol, &in_ring[2][0][0]);
        asm volatile("s_waitcnt vmcnt(32)" ::: "memory");  // chunk 0 landed
    } else if (wid == 0) {
        mem = membrane[bb * LIF_D + ch0 + lane];
    }
    __builtin_amdgcn_s_barrier();
    asm volatile("" ::: "memory");

    for (int h = 0; h < NH; ++h) {
        if (wid == 0) {
            // ---- consumer: chunk h from in_ring, spikes to out_ring ----
            const float* ib = &in_ring [h & 3][0][lane];
            float*       ob = &out_ring[h & 1][0][lane];

            float pre[8], nxt[8];
            #pragma unroll
            for (int j = 0; j < 8; ++j) pre[j] = ib[j * 64];

            for (int r0 = 0; r0 < CHUNK; r0 += 8) {
                if (r0 + 8 < CHUNK) {
                    #pragma unroll
                    for (int j = 0; j < 8; ++j) nxt[j] = ib[(r0 + 8 + j) * 64];
                }
                #pragma unroll
                for (int j = 0; j < 8; ++j) {
                    const float v = 0.9f * mem + pre[j];   // mul-then-add
                    const float w = v - 1.0f;              // off critical path
                    const bool  f = (v >= 1.0f);
                    ob[(r0 + j) * 64] = f ? 1.0f : 0.0f;
                    mem = f ? w : v;                       // soft reset
                }
                #pragma unroll
                for (int j = 0; j < 8; ++j) pre[j] = nxt[j];
            }
            asm volatile("s_waitcnt lgkmcnt(0)" ::: "memory");
        } else if (wid == 1) {
            // ---- producer: stage chunk h+3; keep 32 loads in flight ----
            if (h + 3 < NH) {
                stage_chunk(gbase, (h + 3) * CHUNK, prow, pcol,
                            &in_ring[(h + 3) & 3][0][0]);
                asm volatile("s_waitcnt vmcnt(32)" ::: "memory");
            } else {
                asm volatile("s_waitcnt vmcnt(0)" ::: "memory");
            }
        } else {
            // ---- writers: flush out[h-1] (8 x 1KB each) ----
            if (h >= 1) {
                const int tbase = (h - 1) * CHUNK;
                const float4* o4 = (const float4*)&out_ring[(h - 1) & 1][0][0];
                #pragma unroll
                for (int k = 0; k < 8; ++k) {
                    const int f = (wid - 2) + 2 * k;
                    const float4 vv = o4[f * 64 + lane];
                    const int    t  = tbase + 4 * f + prow;
                    *(float4*)(sbase + (size_t)t * LIF_D + pcol) = vv;
                }
                asm volatile("s_waitcnt lgkmcnt(0)" ::: "memory");
            }
        }
        __builtin_amdgcn_s_barrier();
        asm volatile("" ::: "memory");
    }

    // ---- epilogue: flush out[NH-1]; store final membrane ----
    if (wid >= 2) {
        const int tbase = (NH - 1) * CHUNK;
        const float4* o4 = (const float4*)&out_ring[(NH - 1) & 1][0][0];
        #pragma unroll
        for (int k = 0; k < 8; ++k) {
            const int f = (wid - 2) + 2 * k;
            const float4 vv = o4[f * 64 + lane];
            const int    t  = tbase + 4 * f + prow;
            *(float4*)(sbase + (size_t)t * LIF_D + pcol) = vv;
        }
    } else if (wid == 0) {
        mem_out[bb * LIF_D + ch0 + lane] = mem;
    }
}

extern "C" void kernel_launch(void* const* d_in, const int* in_sizes, int n_in,
                              void* d_out, int out_size, void* d_ws, size_t ws_size,
                              hipStream_t stream) {
    const float* current  = (const float*)d_in[0];   // [8, 4096, 1024]
    const float* membrane = (const float*)d_in[1];   // [8, 1024]

    float* spikes  = (float*)d_out;                                 // [8,4096,1024]
    float* mem_out = (float*)d_out + (size_t)LIF_B * LIF_S * LIF_D; // [8,1024]

    dim3 block(256);                   // w0 consumer, w1 producer, w2-3 writers
    dim3 grid(LIF_B * LIF_D / 64);     // 128 blocks (64 channels each)

    hipLaunchKernelGGL(lif_v5_kernel, grid, block, 0, stream,
                       current, membrane, spikes, mem_out);
}